// Round 5
// baseline (50.293 us; speedup 1.0000x reference)
//
#include <hip/hip_runtime.h>

#define B_SIZE 16384
#define K_NEG 20
#define DIM 128
#define NROWS 21            // target + 20 negatives
#define CHUNK 7             // rows per fenced issue group

// Fast stable log-sigmoid: logsig(x) = min(x,0) - log(1 + exp(-|x|)).
__device__ __forceinline__ float logsig(float x) {
    return fminf(x, 0.0f) - __logf(1.0f + __expf(-fabsf(x)));
}

// 2 batch elements per wave: 32 lanes x one float4 covers a 512 B row in
// ONE instruction. 8192 waves (2048 blocks) -> 32 waves/CU possible, double
// every previous round. __launch_bounds__(256,8) caps VGPR at 64 so we
// actually get 8 waves/SIMD (m69: occupancy halves above 64 VGPRs).
__global__ __launch_bounds__(256, 8) void skipgram_loss_kernel(
    const int* __restrict__ center,
    const int* __restrict__ target,
    const int* __restrict__ neg,
    const float* __restrict__ V,
    const float* __restrict__ U,
    float* __restrict__ accum)
{
    const int tid  = threadIdx.x;
    const int lane = tid & 63;
    const int wid  = tid >> 6;
    const int sub  = lane >> 5;      // element within the wave [0,2)
    const int sl   = lane & 31;      // float4 slot within the 128-float row

    const int e = blockIdx.x * 8 + wid * 2 + sub;   // batch element

    // center embedding (V row): 32 lanes x 16 B
    const float4 ce = ((const float4*)(V + (size_t)center[e] * DIM))[sl];

    const int* nb = neg + e * K_NEG;

    // chunk-0 indices (row 0 = target, rows 1.. = negatives)
    int idxc[CHUNK];
    idxc[0] = target[e];
    #pragma unroll
    for (int r = 1; r < CHUNK; ++r) idxc[r] = nb[r - 1];

    float acc = 0.0f;
    #pragma unroll
    for (int ch = 0; ch < 3; ++ch) {
        // issue this chunk's 7 row-gathers (one dwordx4 instr each)
        float4 a[CHUNK];
        #pragma unroll
        for (int r = 0; r < CHUNK; ++r)
            a[r] = ((const float4*)(U + (size_t)idxc[r] * DIM))[sl];

        // prefetch next chunk's indices while gathers are in flight
        int idxn[CHUNK];
        if (ch < 2) {
            #pragma unroll
            for (int r = 0; r < CHUNK; ++r)
                idxn[r] = nb[(ch + 1) * CHUNK + r - 1];
        }
        // Fence: loads above may not sink past, consumers below may not hoist.
        __builtin_amdgcn_sched_barrier(0);

        float part[CHUNK];
        #pragma unroll
        for (int r = 0; r < CHUNK; ++r)
            part[r] = a[r].x * ce.x + a[r].y * ce.y + a[r].z * ce.z + a[r].w * ce.w;

        // 5-step butterfly within each 32-lane group (xor masks < 32).
        #pragma unroll
        for (int s = 1; s < 32; s <<= 1) {
            #pragma unroll
            for (int r = 0; r < CHUNK; ++r)
                part[r] += __shfl_xor(part[r], s, 64);
        }

        #pragma unroll
        for (int r = 0; r < CHUNK; ++r)
            acc += logsig((ch == 0 && r == 0) ? part[r] : -part[r]);

        if (ch < 2) {
            #pragma unroll
            for (int r = 0; r < CHUNK; ++r) idxc[r] = idxn[r];
        }
    }

    // Wave total: each 32-lane group's lane 0 holds its element's sum.
    float v = (sl == 0) ? acc : 0.0f;
    v += __shfl_xor(v, 32, 64);

    __shared__ float ssum[4];
    if (lane == 0) ssum[wid] = v;
    __syncthreads();
    if (tid == 0)
        atomicAdd(accum, ssum[0] + ssum[1] + ssum[2] + ssum[3]);
}

__global__ void finalize_kernel(const float* __restrict__ accum,
                                float* __restrict__ out)
{
    out[0] = -accum[0] * (1.0f / (float)B_SIZE);
}

extern "C" void kernel_launch(void* const* d_in, const int* in_sizes, int n_in,
                              void* d_out, int out_size, void* d_ws, size_t ws_size,
                              hipStream_t stream) {
    const int*   center = (const int*)d_in[0];
    const int*   target = (const int*)d_in[1];
    const int*   neg    = (const int*)d_in[2];
    const float* V      = (const float*)d_in[3];
    const float* U      = (const float*)d_in[4];
    float* out   = (float*)d_out;
    float* accum = (float*)d_ws;

    hipMemsetAsync(accum, 0, sizeof(float), stream);

    // 8 elements per 256-thread block (4 waves x 2 elements/wave)
    skipgram_loss_kernel<<<B_SIZE / 8, 256, 0, stream>>>(center, target, neg, V, U, accum);
    finalize_kernel<<<1, 1, 0, stream>>>(accum, out);
}